// Round 7
// baseline (28.058 us; speedup 1.0000x reference)
//
#include <hip/hip_runtime.h>
#include <hip/hip_bf16.h>

#define D 128
#define Nn 512
#define Bb 2

typedef __bf16 bf16x8_t __attribute__((ext_vector_type(8)));
typedef float f32x4_t __attribute__((ext_vector_type(4)));
typedef float f32x8_t __attribute__((ext_vector_type(8)));

// ---------------------------------------------------------------------------
// Kernel 1: A[b,i,e] = (dom*evo)@W1[:D] + b1 ;  C[b,i,e] = (dom*evo)@W1[D:]
// (both f32).  4 rows per block, W1 column stream shared 4-ways, unroll 16.
// Blocks 0..7 additionally emit W2T[e][k] = bf16(W2[k][e])  (64 x 128, 16 KB).
// ---------------------------------------------------------------------------
__global__ __launch_bounds__(256)
void precompute_ac(const float* __restrict__ dom, const float* __restrict__ evo,
                   const float* __restrict__ W1, const float* __restrict__ b1,
                   const float* __restrict__ W2,
                   float* __restrict__ A, float* __restrict__ C,
                   __bf16* __restrict__ W2T) {
    const int t = threadIdx.x;
    const int base = blockIdx.x * 4;
    if (blockIdx.x < 8) {
#pragma unroll
        for (int z = 0; z < 4; ++z) {
            int idx = z * 256 + t;                 // 0..1023
            int e = blockIdx.x * 8 + (idx >> 7);   // 8 e-rows per block
            int k = idx & 127;
            W2T[e * 128 + k] = (__bf16)W2[k * 64 + e];
        }
    }
    __shared__ float g4[4][D];
#pragma unroll
    for (int it = 0; it < 2; ++it) {
        int idx = it * 256 + t;
        int r = idx >> 7, c = idx & 127;
        size_t off = (size_t)(base + r) * D + c;
        g4[r][c] = dom[off] * evo[off];
    }
    __syncthreads();
    const int half = t >> 7;                       // 0 -> A, 1 -> C
    const int e = t & 127;
    const float* Wp = W1 + half * D * D;
    float a0 = 0.f, a1 = 0.f, a2 = 0.f, a3 = 0.f;
#pragma unroll 16
    for (int dp = 0; dp < D; ++dp) {
        float w = Wp[dp * D + e];
        a0 = fmaf(g4[0][dp], w, a0);
        a1 = fmaf(g4[1][dp], w, a1);
        a2 = fmaf(g4[2][dp], w, a2);
        a3 = fmaf(g4[3][dp], w, a3);
    }
    if (half == 0) {
        float bb = b1[e];
        A[(size_t)(base + 0) * D + e] = a0 + bb;
        A[(size_t)(base + 1) * D + e] = a1 + bb;
        A[(size_t)(base + 2) * D + e] = a2 + bb;
        A[(size_t)(base + 3) * D + e] = a3 + bb;
    } else {
        C[(size_t)(base + 0) * D + e] = a0;
        C[(size_t)(base + 1) * D + e] = a1;
        C[(size_t)(base + 2) * D + e] = a2;
        C[(size_t)(base + 3) * D + e] = a3;
    }
}

// sum across each 16-lane row via DPP row_shr; FULL SUM LANDS IN ROW-LANE 15
// (row_shr:n -> lane i reads lane i-n, accumulation flows toward lane 15).
__device__ __forceinline__ float row16_reduce(float x) {
    int v = __builtin_bit_cast(int, x);
    x += __builtin_bit_cast(float, __builtin_amdgcn_update_dpp(0, v, 0x118, 0xf, 0xf, false));
    v = __builtin_bit_cast(int, x);
    x += __builtin_bit_cast(float, __builtin_amdgcn_update_dpp(0, v, 0x114, 0xf, 0xf, false));
    v = __builtin_bit_cast(int, x);
    x += __builtin_bit_cast(float, __builtin_amdgcn_update_dpp(0, v, 0x112, 0xf, 0xf, false));
    v = __builtin_bit_cast(int, x);
    x += __builtin_bit_cast(float, __builtin_amdgcn_update_dpp(0, v, 0x111, 0xf, 0xf, false));
    return x;
}

// ---------------------------------------------------------------------------
// Kernel 2: grid = the 1152 active (b, i-group-4, j-chunk-64) units.
// 4 waves, wave = one i.  Only C staged in LDS (32 KB f32, 16B-granule XOR
// swizzle key=row&7).  Phase A: build all H fragments (af, 64 VGPR) once.
// Phase B: et-outer, W2 frags double-buffered straight from L2 (no LDS).
// Phase C: DPP row-reduce (VALU, no LDS; result in m==15), sigmoid, park.
// Upper rows stored coalesced; lower mirror as 16B column segments.
// ---------------------------------------------------------------------------
__global__ __launch_bounds__(256, 3)
void coevo_main(const float* __restrict__ A, const float* __restrict__ Cm,
                const __bf16* __restrict__ W2T, const float* __restrict__ b2,
                const float* __restrict__ W3, const float* __restrict__ b3,
                float* __restrict__ out) {
    const int tid  = threadIdx.x;
    const int wave = tid >> 6;
    const int lane = tid & 63;
    const int m = lane & 15;
    const int q = lane >> 4;

    int u = blockIdx.x;
    const int b = (u >= 576) ? 1 : 0;
    u -= b * 576;
    int chunk = 0;
#pragma unroll
    for (int cc = 1; cc < 8; ++cc) if (u >= 8 * cc * (cc + 1)) chunk = cc;
    const int g = u - 8 * chunk * (chunk + 1);     // 0 .. 16*(chunk+1)-1
    const int i = g * 4 + wave;
    const int i0 = g * 4;

    __shared__ float cs[64 * 128];                 // 32 KB, swizzled
    __shared__ float tile[4][64];                  // block output tile

    // ---- stage C chunk (f32): 2048 granules of 16B, 8 per thread
    const f32x4_t* Cg = (const f32x4_t*)(Cm + ((size_t)b * Nn + (size_t)chunk * 64) * D);
    f32x4_t* csv = (f32x4_t*)cs;
#pragma unroll
    for (int it = 0; it < 8; ++it) {
        int f = it * 256 + tid;
        int r = f >> 5, gi = f & 31;
        csv[r * 32 + (gi ^ (r & 7))] = Cg[f];
    }

    // ---- per-lane A row (b1 folded): abv[kk][e] = A[b,i, kk*32 + q*8 + e]
    f32x8_t abv[4];
    {
        const float* Ap = A + ((size_t)(b * Nn + i)) * D + q * 8;
#pragma unroll
        for (int kk = 0; kk < 4; ++kk) {
            f32x4_t v0 = *(const f32x4_t*)(Ap + kk * 32);
            f32x4_t v1 = *(const f32x4_t*)(Ap + kk * 32 + 4);
            f32x8_t v;
            v[0] = v0[0]; v[1] = v0[1]; v[2] = v0[2]; v[3] = v0[3];
            v[4] = v1[0]; v[5] = v1[1]; v[6] = v1[2]; v[7] = v1[3];
            abv[kk] = v;
        }
    }

    // ---- epilogue constants for this lane's columns e = et*16 + m
    float b2v[4], w3v[4];
#pragma unroll
    for (int et = 0; et < 4; ++et) {
        b2v[et] = b2[et * 16 + m];
        w3v[et] = W3[et * 16 + m];
    }
    const float b3s = b3[0];

    __syncthreads();

    // ---- Phase A: build H fragments for all active j-tiles (held across et)
    bool act[4];
    bf16x8_t af[4][4];
#pragma unroll
    for (int jt = 0; jt < 4; ++jt) {
        act[jt] = (chunk * 64 + jt * 16 + 15 >= i);
        if (!act[jt]) continue;
        const int r0  = jt * 16 + m;
        const int key = r0 & 7;
        const f32x4_t* base = (const f32x4_t*)cs + r0 * 32;
#pragma unroll
        for (int kk = 0; kk < 4; ++kk) {
            const int g0 = kk * 8 + q * 2;
            f32x4_t c0 = base[g0 ^ key];
            f32x4_t c1 = base[(g0 + 1) ^ key];
            f32x8_t c8;
            c8[0] = c0[0]; c8[1] = c0[1]; c8[2] = c0[2]; c8[3] = c0[3];
            c8[4] = c1[0]; c8[5] = c1[1]; c8[6] = c1[2]; c8[7] = c1[3];
            f32x8_t t8 = __builtin_elementwise_max(abv[kk] + c8, (f32x8_t)0.f);
            af[jt][kk] = __builtin_convertvector(t8, bf16x8_t);
        }
    }

    // ---- Phase B: et-outer GEMM, W2 frags double-buffered from global (L2)
    const bf16x8_t* W2g = (const bf16x8_t*)W2T;    // frag idx = e*16 + kk*4 + q
    bf16x8_t wf[2][4];
#pragma unroll
    for (int kk = 0; kk < 4; ++kk)
        wf[0][kk] = W2g[(0 * 16 + m) * 16 + kk * 4 + q];

    float part[4][4] = {{0.f}};
#pragma unroll
    for (int et = 0; et < 4; ++et) {
        if (et < 3) {
#pragma unroll
            for (int kk = 0; kk < 4; ++kk)
                wf[(et + 1) & 1][kk] = W2g[((et + 1) * 16 + m) * 16 + kk * 4 + q];
        }
#pragma unroll
        for (int jt = 0; jt < 4; ++jt) {
            if (!act[jt]) continue;
            f32x4_t a = {0.f, 0.f, 0.f, 0.f};
#pragma unroll
            for (int kk = 0; kk < 4; ++kk)
                a = __builtin_amdgcn_mfma_f32_16x16x32_bf16(af[jt][kk], wf[et & 1][kk], a, 0, 0, 0);
#pragma unroll
            for (int r = 0; r < 4; ++r)
                part[jt][r] = fmaf(fmaxf(a[r] + b2v[et], 0.f), w3v[et], part[jt][r]);
        }
    }

    // ---- Phase C: DPP reduce over 16 e-lanes (result in m==15), sigmoid
#pragma unroll
    for (int jt = 0; jt < 4; ++jt) {
        if (!act[jt]) continue;
        float red[4];
#pragma unroll
        for (int r = 0; r < 4; ++r) red[r] = row16_reduce(part[jt][r]);
        if (m == 15) {
#pragma unroll
            for (int r = 0; r < 4; ++r) {
                int jc = jt * 16 + q * 4 + r;
                tile[wave][jc] = 1.f / (1.f + expf(-(red[r] + b3s)));
            }
        }
    }

    __syncthreads();

    // ---- upper store: row i, 64 cols (coalesced f32x4), diag = 0
    if ((tid & 63) < 16) {
        const int c4 = tid & 15;
        const int j0 = chunk * 64 + c4 * 4;
        float v0 = tile[wave][c4 * 4 + 0];
        float v1 = tile[wave][c4 * 4 + 1];
        float v2 = tile[wave][c4 * 4 + 2];
        float v3 = tile[wave][c4 * 4 + 3];
        float* op = out + ((size_t)b * Nn + i) * Nn + j0;
        if (j0 > i) {
            f32x4_t v; v[0] = v0; v[1] = v1; v[2] = v2; v[3] = v3;
            *(f32x4_t*)op = v;
        } else if (j0 + 3 >= i) {                  // straddles diagonal
            if (j0 + 0 > i) op[0] = v0; else if (j0 + 0 == i) op[0] = 0.f;
            if (j0 + 1 > i) op[1] = v1; else if (j0 + 1 == i) op[1] = 0.f;
            if (j0 + 2 > i) op[2] = v2; else if (j0 + 2 == i) op[2] = 0.f;
            if (j0 + 3 > i) op[3] = v3; else if (j0 + 3 == i) op[3] = 0.f;
        }                                          // else fully below diag: skip
    }
    // ---- lower (mirror) store: 64 rows j, cols i0..i0+3 (16B segments)
    if (tid < 64) {
        const int j = chunk * 64 + tid;
        float v0 = tile[0][tid], v1 = tile[1][tid], v2 = tile[2][tid], v3 = tile[3][tid];
        float* op = out + ((size_t)b * Nn + j) * Nn + i0;
        if (j > i0 + 3) {
            f32x4_t v; v[0] = v0; v[1] = v1; v[2] = v2; v[3] = v3;
            *(f32x4_t*)op = v;
        } else {
            if (j > i0 + 0) op[0] = v0;
            if (j > i0 + 1) op[1] = v1;
            if (j > i0 + 2) op[2] = v2;
            if (j > i0 + 3) op[3] = v3;
        }
    }
}

extern "C" void kernel_launch(void* const* d_in, const int* in_sizes, int n_in,
                              void* d_out, int out_size, void* d_ws, size_t ws_size,
                              hipStream_t stream) {
    const float* dom = (const float*)d_in[0];
    const float* evo = (const float*)d_in[1];
    const float* W1  = (const float*)d_in[2];
    const float* b1  = (const float*)d_in[3];
    const float* W2  = (const float*)d_in[4];
    const float* b2  = (const float*)d_in[5];
    const float* W3  = (const float*)d_in[6];
    const float* b3  = (const float*)d_in[7];
    float* out = (float*)d_out;

    float*  A   = (float*)d_ws;                          // [B][N][D] f32 (512 KB)
    float*  C   = A + (size_t)Bb * Nn * D;               // [B][N][D] f32 (512 KB)
    __bf16* W2T = (__bf16*)(C + (size_t)Bb * Nn * D);    // [64][128] bf16 (16 KB)

    precompute_ac<<<Bb * Nn / 4, 256, 0, stream>>>(dom, evo, W1, b1, W2, A, C, W2T);
    coevo_main<<<Bb * 576, 256, 0, stream>>>(A, C, W2T, b2, W3, b3, out);
}

// Round 8
// 25.691 us; speedup vs baseline: 1.0921x; 1.0921x over previous
//
#include <hip/hip_runtime.h>
#include <hip/hip_bf16.h>

#define D 128
#define Nn 512
#define Bb 2

typedef __bf16 bf16x8_t __attribute__((ext_vector_type(8)));
typedef unsigned short u16x8_t __attribute__((ext_vector_type(8)));
typedef float f32x4_t __attribute__((ext_vector_type(4)));
typedef float f32x8_t __attribute__((ext_vector_type(8)));

// ---------------------------------------------------------------------------
// Kernel 1: A16[b,i,e] = bf16((dom*evo)@W1[:D] + b1); C16[b,i,e] = bf16((dom*evo)@W1[D:])
// 2 rows per block (512 blocks, 2/CU), W1 column stream shared 2-ways.
// Blocks 0..7 additionally emit W2T[e][k] = bf16(W2[k][e])  (64 x 128, 16 KB).
// ---------------------------------------------------------------------------
__global__ __launch_bounds__(256)
void precompute_ac(const float* __restrict__ dom, const float* __restrict__ evo,
                   const float* __restrict__ W1, const float* __restrict__ b1,
                   const float* __restrict__ W2,
                   __bf16* __restrict__ A16, __bf16* __restrict__ C16,
                   __bf16* __restrict__ W2T) {
    const int t = threadIdx.x;
    const int base = blockIdx.x * 2;
    if (blockIdx.x < 8) {
#pragma unroll
        for (int z = 0; z < 4; ++z) {
            int idx = z * 256 + t;                 // 0..1023
            int e = blockIdx.x * 8 + (idx >> 7);   // 8 e-rows per block
            int k = idx & 127;
            W2T[e * 128 + k] = (__bf16)W2[k * 64 + e];
        }
    }
    __shared__ float g2[2][D];
    {
        int r = t >> 7, c = t & 127;
        size_t off = (size_t)(base + r) * D + c;
        g2[r][c] = dom[off] * evo[off];
    }
    __syncthreads();
    const int half = t >> 7;                       // 0 -> A, 1 -> C
    const int e = t & 127;
    const float* Wp = W1 + half * D * D;
    float a0 = 0.f, a1 = 0.f;
#pragma unroll 16
    for (int dp = 0; dp < D; ++dp) {
        float w = Wp[dp * D + e];
        a0 = fmaf(g2[0][dp], w, a0);
        a1 = fmaf(g2[1][dp], w, a1);
    }
    if (half == 0) {
        float bb = b1[e];
        A16[(size_t)(base + 0) * D + e] = (__bf16)(a0 + bb);
        A16[(size_t)(base + 1) * D + e] = (__bf16)(a1 + bb);
    } else {
        C16[(size_t)(base + 0) * D + e] = (__bf16)a0;
        C16[(size_t)(base + 1) * D + e] = (__bf16)a1;
    }
}

// sum across each 16-lane row via DPP row_shr; FULL SUM LANDS IN ROW-LANE 15.
__device__ __forceinline__ float row16_reduce(float x) {
    int v = __builtin_bit_cast(int, x);
    x += __builtin_bit_cast(float, __builtin_amdgcn_update_dpp(0, v, 0x118, 0xf, 0xf, false));
    v = __builtin_bit_cast(int, x);
    x += __builtin_bit_cast(float, __builtin_amdgcn_update_dpp(0, v, 0x114, 0xf, 0xf, false));
    v = __builtin_bit_cast(int, x);
    x += __builtin_bit_cast(float, __builtin_amdgcn_update_dpp(0, v, 0x112, 0xf, 0xf, false));
    v = __builtin_bit_cast(int, x);
    x += __builtin_bit_cast(float, __builtin_amdgcn_update_dpp(0, v, 0x111, 0xf, 0xf, false));
    return x;
}

// ---------------------------------------------------------------------------
// Kernel 2: grid = the 1152 active (b, i-group-4, j-chunk-64) units.
// 4 waves, wave = one i.  NO C staging: c-fragments read straight from L2/LLC
// per jt (C is 256 KB bf16, read-shared chip-wide).  LDS = W2T (16 KB,
// 16B-granule XOR swizzle key=row&15) + output tile (1 KB) -> 17 KB.
// __launch_bounds__(256,5): <=96 VGPR -> 5 blocks/CU -> whole grid resident.
// DPP row-reduce (result in m==15), sigmoid; upper rows stored coalesced,
// lower mirror as 16B column segments. Diagonal = 0.
// ---------------------------------------------------------------------------
__global__ __launch_bounds__(256, 5)
void coevo_main(const __bf16* __restrict__ A16, const __bf16* __restrict__ Cm,
                const __bf16* __restrict__ W2T, const float* __restrict__ b2,
                const float* __restrict__ W3, const float* __restrict__ b3,
                float* __restrict__ out) {
    const int tid  = threadIdx.x;
    const int wave = tid >> 6;
    const int lane = tid & 63;
    const int m = lane & 15;
    const int q = lane >> 4;

    int u = blockIdx.x;
    const int b = (u >= 576) ? 1 : 0;
    u -= b * 576;
    int chunk = 0;
#pragma unroll
    for (int cc = 1; cc < 8; ++cc) if (u >= 8 * cc * (cc + 1)) chunk = cc;
    const int g = u - 8 * chunk * (chunk + 1);     // 0 .. 16*(chunk+1)-1
    const int i = g * 4 + wave;
    const int i0 = g * 4;

    __shared__ __bf16 w2s[64 * 128];               // 16 KB, swizzled
    __shared__ float  tile[4][64];                 // block output tile

    // ---- A row (bf16, b1 folded): 4 x 16B loads, issued first
    const u16x8_t* Ag8 = (const u16x8_t*)(A16 + ((size_t)(b * Nn + i)) * D);
    u16x8_t ab16[4];
#pragma unroll
    for (int kk = 0; kk < 4; ++kk) ab16[kk] = Ag8[kk * 4 + q];

    // ---- stage W2T into LDS: 1024 granules of 16B, 4 per thread, swizzled
    {
        f32x4_t* w2v = (f32x4_t*)w2s;
        const f32x4_t* W2Tg = (const f32x4_t*)W2T;
#pragma unroll
        for (int it = 0; it < 4; ++it) {
            int f = it * 256 + tid;
            int r = f >> 4, gi = f & 15;
            w2v[r * 16 + (gi ^ (r & 15))] = W2Tg[f];
        }
    }

    // ---- expand A to f32 once (32 VGPR)
    f32x8_t abv[4];
#pragma unroll
    for (int kk = 0; kk < 4; ++kk) {
#pragma unroll
        for (int z = 0; z < 8; ++z)
            abv[kk][z] = __builtin_bit_cast(float, (unsigned)ab16[kk][z] << 16);
    }

    // ---- epilogue constants for this lane's columns e = et*16 + m
    float b2v[4], w3v[4];
#pragma unroll
    for (int et = 0; et < 4; ++et) {
        b2v[et] = b2[et * 16 + m];
        w3v[et] = W3[et * 16 + m];
    }
    const float b3s = b3[0];

    __syncthreads();

    const u16x8_t*  Cg8 = (const u16x8_t*)(Cm + ((size_t)b * Nn + (size_t)chunk * 64) * D);
    const bf16x8_t* w2r = (const bf16x8_t*)w2s;

#pragma unroll
    for (int jt = 0; jt < 4; ++jt) {
        if (chunk * 64 + jt * 16 + 15 < i) continue;   // tile entirely below diag
        const int r0 = jt * 16 + m;                    // this lane's j row

        // ---- build H fragments: h = relu(a + c), c straight from L2/LLC
        bf16x8_t af[4];
#pragma unroll
        for (int kk = 0; kk < 4; ++kk) {
            u16x8_t cr = Cg8[r0 * 16 + kk * 4 + q];
            f32x8_t c8;
#pragma unroll
            for (int z = 0; z < 8; ++z)
                c8[z] = __builtin_bit_cast(float, (unsigned)cr[z] << 16);
            f32x8_t t8 = __builtin_elementwise_max(abv[kk] + c8, (f32x8_t)0.f);
            af[kk] = __builtin_convertvector(t8, bf16x8_t);
        }

        // ---- GEMM + epilogue fused per et (acc stays at 4 VGPR)
        float part[4] = {0.f, 0.f, 0.f, 0.f};
#pragma unroll
        for (int et = 0; et < 4; ++et) {
            bf16x8_t wf[4];
#pragma unroll
            for (int kk = 0; kk < 4; ++kk)
                wf[kk] = w2r[(et * 16 + m) * 16 + ((kk * 4 + q) ^ m)];
            f32x4_t a = {0.f, 0.f, 0.f, 0.f};
#pragma unroll
            for (int kk = 0; kk < 4; ++kk)
                a = __builtin_amdgcn_mfma_f32_16x16x32_bf16(af[kk], wf[kk], a, 0, 0, 0);
#pragma unroll
            for (int r = 0; r < 4; ++r)
                part[r] = fmaf(fmaxf(a[r] + b2v[et], 0.f), w3v[et], part[r]);
        }

        // ---- DPP reduce over 16 e-lanes (result in m==15), sigmoid, park
        float red[4];
#pragma unroll
        for (int r = 0; r < 4; ++r) red[r] = row16_reduce(part[r]);
        if (m == 15) {
#pragma unroll
            for (int r = 0; r < 4; ++r) {
                int jc = jt * 16 + q * 4 + r;
                tile[wave][jc] = 1.f / (1.f + expf(-(red[r] + b3s)));
            }
        }
    }

    __syncthreads();

    // ---- upper store: row i, 64 cols (coalesced f32x4), diag = 0
    if ((tid & 63) < 16) {
        const int c4 = tid & 15;
        const int j0 = chunk * 64 + c4 * 4;
        float v0 = tile[wave][c4 * 4 + 0];
        float v1 = tile[wave][c4 * 4 + 1];
        float v2 = tile[wave][c4 * 4 + 2];
        float v3 = tile[wave][c4 * 4 + 3];
        float* op = out + ((size_t)b * Nn + i) * Nn + j0;
        if (j0 > i) {
            f32x4_t v; v[0] = v0; v[1] = v1; v[2] = v2; v[3] = v3;
            *(f32x4_t*)op = v;
        } else if (j0 + 3 >= i) {                  // straddles diagonal
            if (j0 + 0 > i) op[0] = v0; else if (j0 + 0 == i) op[0] = 0.f;
            if (j0 + 1 > i) op[1] = v1; else if (j0 + 1 == i) op[1] = 0.f;
            if (j0 + 2 > i) op[2] = v2; else if (j0 + 2 == i) op[2] = 0.f;
            if (j0 + 3 > i) op[3] = v3; else if (j0 + 3 == i) op[3] = 0.f;
        }                                          // else fully below diag: skip
    }
    // ---- lower (mirror) store: 64 rows j, cols i0..i0+3 (16B segments)
    if (tid < 64) {
        const int j = chunk * 64 + tid;
        float v0 = tile[0][tid], v1 = tile[1][tid], v2 = tile[2][tid], v3 = tile[3][tid];
        float* op = out + ((size_t)b * Nn + j) * Nn + i0;
        if (j > i0 + 3) {
            f32x4_t v; v[0] = v0; v[1] = v1; v[2] = v2; v[3] = v3;
            *(f32x4_t*)op = v;
        } else {
            if (j > i0 + 0) op[0] = v0;
            if (j > i0 + 1) op[1] = v1;
            if (j > i0 + 2) op[2] = v2;
            if (j > i0 + 3) op[3] = v3;
        }
    }
}

extern "C" void kernel_launch(void* const* d_in, const int* in_sizes, int n_in,
                              void* d_out, int out_size, void* d_ws, size_t ws_size,
                              hipStream_t stream) {
    const float* dom = (const float*)d_in[0];
    const float* evo = (const float*)d_in[1];
    const float* W1  = (const float*)d_in[2];
    const float* b1  = (const float*)d_in[3];
    const float* W2  = (const float*)d_in[4];
    const float* b2  = (const float*)d_in[5];
    const float* W3  = (const float*)d_in[6];
    const float* b3  = (const float*)d_in[7];
    float* out = (float*)d_out;

    __bf16* A16 = (__bf16*)d_ws;                         // [B][N][D] bf16 (256 KB)
    __bf16* C16 = A16 + (size_t)Bb * Nn * D;             // [B][N][D] bf16 (256 KB)
    __bf16* W2T = C16 + (size_t)Bb * Nn * D;             // [64][128] bf16 (16 KB)

    precompute_ac<<<Bb * Nn / 2, 256, 0, stream>>>(dom, evo, W1, b1, W2, A16, C16, W2T);
    coevo_main<<<Bb * 576, 256, 0, stream>>>(A16, C16, W2T, b2, W3, b3, out);
}